// Round 9
// baseline (217.905 us; speedup 1.0000x reference)
//
#include <hip/hip_runtime.h>
#include <stdint.h>

typedef unsigned short u16;
typedef __attribute__((ext_vector_type(8))) short bf16x8;   // 8 bf16 in 4 VGPRs
typedef __attribute__((ext_vector_type(4))) float f32x4;

#define B_   16
#define C_   256
#define HW_  4096
#define HID_ 128

__device__ __forceinline__ float b2f(u16 u) {
  union { uint32_t i; float f; } v; v.i = ((uint32_t)u) << 16; return v.f;
}
__device__ __forceinline__ u16 f2b(float f) {
  union { float f; uint32_t i; } v; v.f = f;
  uint32_t r = (v.i + 0x7FFFu + ((v.i >> 16) & 1u)) >> 16;
  return (u16)r;
}

// ---------------------------------------------------------------------------
// K1: heterogeneous: [0,512) GroupNorm stats; [512,608) convert qkv_w->bf16;
// [608,1636) zero Weff+cvec (263168 float4s).
// ---------------------------------------------------------------------------
__global__ __launch_bounds__(256) void gn_stats_conv_kernel(
    const float* __restrict__ x, const float* __restrict__ gnw,
    const float* __restrict__ gnb, float* __restrict__ scale,
    float* __restrict__ shiftv,
    const float* __restrict__ qkvw, u16* __restrict__ cqkvw,
    float* __restrict__ weff_zero)
{
  if (blockIdx.x >= 608) {
    int gid = (blockIdx.x - 608) * 256 + threadIdx.x;
    if (gid < 263168) ((float4*)weff_zero)[gid] = make_float4(0.f, 0.f, 0.f, 0.f);
    return;
  }
  if (blockIdx.x >= 512) {
    int i = (blockIdx.x - 512) * 256 + threadIdx.x;   // < 24576 exactly
    float4 f = ((const float4*)qkvw)[i];
    ushort4 o;
    o.x = f2b(f.x); o.y = f2b(f.y); o.z = f2b(f.z); o.w = f2b(f.w);
    ((ushort4*)cqkvw)[i] = o;
    return;
  }
  int b = blockIdx.x >> 5, g = blockIdx.x & 31;
  const float* p = x + ((size_t)b * C_ + g * 8) * HW_;
  int t = threadIdx.x;
  float s = 0.f, sq = 0.f;
#pragma unroll
  for (int i = 0; i < 16; ++i) {
    float4 u0 = *(const float4*)(p + t * 8 + i * 2048);
    float4 u1 = *(const float4*)(p + t * 8 + i * 2048 + 4);
    s  += u0.x + u0.y + u0.z + u0.w + u1.x + u1.y + u1.z + u1.w;
    sq += u0.x*u0.x + u0.y*u0.y + u0.z*u0.z + u0.w*u0.w
        + u1.x*u1.x + u1.y*u1.y + u1.z*u1.z + u1.w*u1.w;
  }
#pragma unroll
  for (int off = 32; off > 0; off >>= 1) {
    s  += __shfl_down(s, off);
    sq += __shfl_down(sq, off);
  }
  __shared__ float ps[4], pq[4], mr[2];
  int lane = t & 63, w = t >> 6;
  if (lane == 0) { ps[w] = s; pq[w] = sq; }
  __syncthreads();
  if (t == 0) {
    float S = ps[0] + ps[1] + ps[2] + ps[3];
    float Q = pq[0] + pq[1] + pq[2] + pq[3];
    float mean = S * (1.f / 32768.f);
    float var  = Q * (1.f / 32768.f) - mean * mean;
    mr[0] = mean; mr[1] = rsqrtf(var + 1e-5f);
  }
  __syncthreads();
  if (t < 8) {
    int c = g * 8 + t;
    float sc = gnw[c] * mr[1];
    scale[b * C_ + c]  = sc;
    shiftv[b * C_ + c] = gnb[c] - mr[0] * sc;
  }
}

// ---------------------------------------------------------------------------
// K2: fused GN-apply + transpose: x fp32 [b][256][4096] -> xn_t bf16
// [b][4096][256]. tile 64 c x 128 n, grid (32, 4, 16).
// ---------------------------------------------------------------------------
__global__ __launch_bounds__(256) void gn_transpose_kernel(
    const float* __restrict__ x, u16* __restrict__ dst,
    const float* __restrict__ scale, const float* __restrict__ shiftv)
{
  int nt = blockIdx.x, ct = blockIdx.y, b = blockIdx.z;
  const float* S = x + (size_t)b * C_ * HW_;
  u16* D = dst + (size_t)b * HW_ * C_;
  __shared__ __align__(16) u16 tile[64][136];
  int t = threadIdx.x;
  int n0 = nt * 128, c0 = ct * 64;
  int r = t >> 2, seg = (t & 3) * 32;
  float sc = scale[(size_t)b * C_ + c0 + r];
  float sh = shiftv[(size_t)b * C_ + c0 + r];
#pragma unroll
  for (int i = 0; i < 4; ++i) {
    const float* rp = S + (size_t)(c0 + r) * HW_ + n0 + seg + i * 8;
    float4 u0 = *(const float4*)(rp);
    float4 u1 = *(const float4*)(rp + 4);
    float f[8] = {u0.x, u0.y, u0.z, u0.w, u1.x, u1.y, u1.z, u1.w};
    uint4 o;
    uint32_t* op = (uint32_t*)&o;
#pragma unroll
    for (int j = 0; j < 4; ++j) {
      op[j] = (uint32_t)f2b(f[2 * j] * sc + sh)
            | ((uint32_t)f2b(f[2 * j + 1] * sc + sh) << 16);
    }
    *(uint4*)&tile[r][seg + i * 8] = o;
  }
  __syncthreads();
#pragma unroll
  for (int i = 0; i < 4; ++i) {
    int m = t * 4 + i;
    int n_l = m >> 3, cg = (m & 7) * 8;
    union { u16 v[8]; uint4 q; } pk;
#pragma unroll
    for (int e = 0; e < 8; ++e) pk.v[e] = tile[cg + e][n_l];
    *(uint4*)(D + (size_t)(n0 + n_l) * C_ + c0 + cg) = pk.q;
  }
}

// ---------------------------------------------------------------------------
// K3: KV GEMM (q deleted). kv[b][o][n] = qkv_w[128+o] @ xn_t^T + bias.
// 128x128 tile, BK=64, global_load_lds. grid (32, 2, 16).
// ---------------------------------------------------------------------------
__global__ __launch_bounds__(256) void kv_gemm_kernel(
    const u16* __restrict__ A, const u16* __restrict__ Bt,
    const float* __restrict__ bias, u16* __restrict__ kv)
{
  const int K = C_;
  int nt = blockIdx.x, mt = blockIdx.y, b = blockIdx.z;
  const u16* Ab = A + (size_t)(128 + mt * 128) * K;
  const u16* Bb = Bt + (size_t)b * HW_ * C_ + (size_t)nt * 128 * K;
  __shared__ __align__(16) u16 lA[128 * 64];
  __shared__ __align__(16) u16 lB[128 * 64];
  int t = threadIdx.x;
  int lane = t & 63, w = t >> 6;
  int quad = lane >> 4, l16 = lane & 15;
  int wm = (w >> 1) * 64, wn = (w & 1) * 64;
  f32x4 acc[4][4];
#pragma unroll
  for (int i = 0; i < 4; ++i)
#pragma unroll
    for (int j = 0; j < 4; ++j)
#pragma unroll
      for (int r = 0; r < 4; ++r) acc[i][j][r] = 0.f;

  for (int k0 = 0; k0 < K; k0 += 64) {
    __syncthreads();
#pragma unroll
    for (int q = 0; q < 4; ++q) {
      int ch = q * 256 + t;
      int row = ch >> 3, off = (ch & 7) * 8;
      __builtin_amdgcn_global_load_lds(
          (const __attribute__((address_space(1))) void*)(Ab + (size_t)row * K + k0 + off),
          (__attribute__((address_space(3))) void*)(lA + ch * 8), 16, 0, 0);
      __builtin_amdgcn_global_load_lds(
          (const __attribute__((address_space(1))) void*)(Bb + (size_t)row * K + k0 + off),
          (__attribute__((address_space(3))) void*)(lB + ch * 8), 16, 0, 0);
    }
    __syncthreads();
    const bf16x8* A8 = (const bf16x8*)lA;
    const bf16x8* B8 = (const bf16x8*)lB;
#pragma unroll
    for (int kk = 0; kk < 2; ++kk) {
      bf16x8 af[4], bfr[4];
#pragma unroll
      for (int i = 0; i < 4; ++i) af[i]  = A8[(wm + i * 16 + l16) * 8 + kk * 4 + quad];
#pragma unroll
      for (int j = 0; j < 4; ++j) bfr[j] = B8[(wn + j * 16 + l16) * 8 + kk * 4 + quad];
#pragma unroll
      for (int i = 0; i < 4; ++i)
#pragma unroll
        for (int j = 0; j < 4; ++j)
          acc[i][j] = __builtin_amdgcn_mfma_f32_16x16x32_bf16(af[i], bfr[j],
                                                              acc[i][j], 0, 0, 0);
    }
  }
#pragma unroll
  for (int i = 0; i < 4; ++i) {
#pragma unroll
    for (int rg = 0; rg < 4; ++rg) {
      int o = mt * 128 + wm + i * 16 + quad * 4 + rg;   // kv row 0..255
      float bsv = bias[128 + o];
      size_t rowbase = ((size_t)b * 256 + o) * HW_;
#pragma unroll
      for (int j = 0; j < 4; ++j) {
        int n = nt * 128 + wn + j * 16 + l16;
        kv[rowbase + n] = f2b(acc[i][j][rg] + bsv);
      }
    }
  }
}

// ---------------------------------------------------------------------------
// K4: softmax + context + weight-fold + Weff partial. grid 64 = (b,h),
// 1024 threads (16 waves).
//   cs[d*32+e]   = sum_n exp(k[hd][n]) v[he][n]   (raw context)
//   sinv[d]      = 1/sum_n exp(k[hd][n])
//   wfl[o][d]    = sum_e outw[o][he]*cs[d][e]*sinv[d]      (bf16, LDS)
//   Weff[b]     += wfl @ Wq_h  (256x32 @ 32x256, MFMA, fp32 atomics)
//   cvec[b][o]  += wfl[o] . bq_h
// ---------------------------------------------------------------------------
__global__ __launch_bounds__(1024) void ctx_weff_kernel(
    const u16* __restrict__ kv, const float* __restrict__ outw,
    const u16* __restrict__ cqkvw, const float* __restrict__ qkvb,
    float* __restrict__ Weff, float* __restrict__ cvec)
{
  int b = blockIdx.x >> 2, h = blockIdx.x & 3;
  const u16* kb = kv + ((size_t)b * 256 + h * 32) * HW_;
  const u16* vb = kv + ((size_t)b * 256 + 128 + h * 32) * HW_;
  __shared__ __align__(16) char sm[78080];
  float*  part = (float*)sm;               // [16][1024]  (dead after cs)
  float*  cs   = (float*)(sm + 65536);     // [1024]
  float2* sred = (float2*)(sm + 69632);    // [1024]
  float*  sinv = (float*)(sm + 77824);     // [32]
  u16* wfl = (u16*)sm;                     // [256][40] bf16 (overlays part)
  u16* wqt = (u16*)(sm + 20480);           // [256][40] bf16 (overlays part)
  int t = threadIdx.x;
  int w = t >> 6, lane = t & 63;
  int quad = lane >> 4, l16 = lane & 15;

  // ---- context partials over this wave's K=256 chunk
  f32x4 acc[2][2];
#pragma unroll
  for (int i = 0; i < 2; ++i)
#pragma unroll
    for (int j = 0; j < 2; ++j)
#pragma unroll
      for (int r = 0; r < 4; ++r) acc[i][j][r] = 0.f;
  float s0 = 0.f, s1 = 0.f;
  int kbase = w * 256;
  for (int it = 0; it < 8; ++it) {
    int n0 = kbase + it * 32 + quad * 8;
    bf16x8 k0 = *(const bf16x8*)(kb + (size_t)l16 * HW_ + n0);
    bf16x8 k1 = *(const bf16x8*)(kb + (size_t)(16 + l16) * HW_ + n0);
    bf16x8 v0 = *(const bf16x8*)(vb + (size_t)l16 * HW_ + n0);
    bf16x8 v1 = *(const bf16x8*)(vb + (size_t)(16 + l16) * HW_ + n0);
    bf16x8 a0, a1;
    const u16* k0p = (const u16*)&k0; u16* a0p = (u16*)&a0;
    const u16* k1p = (const u16*)&k1; u16* a1p = (u16*)&a1;
#pragma unroll
    for (int e = 0; e < 8; ++e) {
      float e0 = __expf(b2f(k0p[e]));
      float e1 = __expf(b2f(k1p[e]));
      s0 += e0; s1 += e1;
      a0p[e] = f2b(e0); a1p[e] = f2b(e1);
    }
    acc[0][0] = __builtin_amdgcn_mfma_f32_16x16x32_bf16(a0, v0, acc[0][0], 0, 0, 0);
    acc[0][1] = __builtin_amdgcn_mfma_f32_16x16x32_bf16(a0, v1, acc[0][1], 0, 0, 0);
    acc[1][0] = __builtin_amdgcn_mfma_f32_16x16x32_bf16(a1, v0, acc[1][0], 0, 0, 0);
    acc[1][1] = __builtin_amdgcn_mfma_f32_16x16x32_bf16(a1, v1, acc[1][1], 0, 0, 0);
  }
#pragma unroll
  for (int i = 0; i < 2; ++i)
#pragma unroll
    for (int j = 0; j < 2; ++j)
#pragma unroll
      for (int r = 0; r < 4; ++r) {
        int d = i * 16 + quad * 4 + r;
        int e = j * 16 + l16;
        part[w * 1024 + d * 32 + e] = acc[i][j][r];
      }
  sred[t] = make_float2(s0, s1);
  __syncthreads();
  {
    float a = 0.f;
#pragma unroll
    for (int ww = 0; ww < 16; ++ww) a += part[ww * 1024 + t];
    cs[t] = a;
  }
  if (t < 32) {
    int d = t, lsel = d & 15;
    float ssum = 0.f;
#pragma unroll
    for (int ww = 0; ww < 16; ++ww)
#pragma unroll
      for (int q = 0; q < 4; ++q) {
        float2 v2 = sred[ww * 64 + q * 16 + lsel];
        ssum += (d < 16) ? v2.x : v2.y;
      }
    sinv[d] = 1.f / ssum;
  }
  __syncthreads();   // cs, sinv ready; part region dead

  // ---- wfl[o][d] (bf16 LDS, stride 40) ; wqt = Wq_h^T (bf16 LDS, stride 40)
  {
    int o = t & 255, dg = t >> 8;
    const float* wr = outw + (size_t)o * HID_ + h * 32;
    float wv[32];
#pragma unroll
    for (int e = 0; e < 32; ++e) wv[e] = wr[e];
#pragma unroll
    for (int dd = 0; dd < 8; ++dd) {
      int d = dg * 8 + dd;
      float a = 0.f;
#pragma unroll
      for (int e = 0; e < 32; ++e) a += wv[e] * cs[d * 32 + e];
      wfl[o * 40 + d] = f2b(a * sinv[d]);
    }
  }
  {
    int d = t >> 5, c0 = (t & 31) * 8;
    bf16x8 r8 = *(const bf16x8*)(cqkvw + (size_t)(h * 32 + d) * 256 + c0);
    const u16* rp = (const u16*)&r8;
#pragma unroll
    for (int e = 0; e < 8; ++e) wqt[(c0 + e) * 40 + d] = rp[e];
  }
  __syncthreads();

  // ---- cvec partial
  if (t < 256) {
    float a = 0.f;
#pragma unroll
    for (int d = 0; d < 32; ++d) a += b2f(wfl[t * 40 + d]) * qkvb[h * 32 + d];
    atomicAdd(&cvec[b * 256 + t], a);
  }

  // ---- Weff partial: 16 waves tile 256x256 as 4x4 of 64x64; K=32 (1 MFMA/frag)
  {
    int ob = (w >> 2) * 64, cb = (w & 3) * 64;
    const bf16x8* A8 = (const bf16x8*)wfl;
    const bf16x8* B8 = (const bf16x8*)wqt;
    bf16x8 af[4], bfr[4];
#pragma unroll
    for (int i = 0; i < 4; ++i) af[i]  = A8[(ob + i * 16 + l16) * 5 + quad];
#pragma unroll
    for (int j = 0; j < 4; ++j) bfr[j] = B8[(cb + j * 16 + l16) * 5 + quad];
    float* Wb = Weff + (size_t)b * 65536;
#pragma unroll
    for (int i = 0; i < 4; ++i)
#pragma unroll
      for (int j = 0; j < 4; ++j) {
        f32x4 wa = {0.f, 0.f, 0.f, 0.f};
        wa = __builtin_amdgcn_mfma_f32_16x16x32_bf16(af[i], bfr[j], wa, 0, 0, 0);
#pragma unroll
        for (int r = 0; r < 4; ++r) {
          int o = ob + i * 16 + quad * 4 + r;
          int c = cb + j * 16 + l16;
          atomicAdd(&Wb[o * 256 + c], wa[r]);
        }
      }
  }
}

// ---------------------------------------------------------------------------
// K5: final GEMM. out[b] = Weff[b](fp32->bf16 inline) @ xn_t^T + outb + cvec.
// 128x128 tile, BK=64, K=256. grid (32, 2, 16). fp32 out.
// ---------------------------------------------------------------------------
__global__ __launch_bounds__(256) void wout_gemm_kernel(
    const float* __restrict__ Weff, const u16* __restrict__ Bt,
    const float* __restrict__ outb, const float* __restrict__ cvec,
    float* __restrict__ Cout)
{
  const int K = C_;
  int nt = blockIdx.x, mt = blockIdx.y, b = blockIdx.z;
  const float* Ab = Weff + (size_t)b * 65536 + (size_t)mt * 128 * 256;
  const u16* Bb = Bt + (size_t)b * HW_ * C_ + (size_t)nt * 128 * K;
  __shared__ __align__(16) u16 lA[128 * 64];
  __shared__ __align__(16) u16 lB[128 * 64];
  int t = threadIdx.x;
  int lane = t & 63, w = t >> 6;
  int quad = lane >> 4, l16 = lane & 15;
  int wm = (w >> 1) * 64, wn = (w & 1) * 64;
  f32x4 acc[4][4];
#pragma unroll
  for (int i = 0; i < 4; ++i)
#pragma unroll
    for (int j = 0; j < 4; ++j)
#pragma unroll
      for (int r = 0; r < 4; ++r) acc[i][j][r] = 0.f;

  for (int k0 = 0; k0 < K; k0 += 64) {
    __syncthreads();
#pragma unroll
    for (int q = 0; q < 4; ++q) {
      int ch = q * 256 + t;
      int row = ch >> 3, off = (ch & 7) * 8;
      // A: fp32 load + convert + LDS store
      float4 f0 = *(const float4*)(Ab + (size_t)row * 256 + k0 + off);
      float4 f1 = *(const float4*)(Ab + (size_t)row * 256 + k0 + off + 4);
      uint4 o;
      o.x = (uint32_t)f2b(f0.x) | ((uint32_t)f2b(f0.y) << 16);
      o.y = (uint32_t)f2b(f0.z) | ((uint32_t)f2b(f0.w) << 16);
      o.z = (uint32_t)f2b(f1.x) | ((uint32_t)f2b(f1.y) << 16);
      o.w = (uint32_t)f2b(f1.z) | ((uint32_t)f2b(f1.w) << 16);
      *(uint4*)(lA + ch * 8) = o;
      // B: async
      __builtin_amdgcn_global_load_lds(
          (const __attribute__((address_space(1))) void*)(Bb + (size_t)row * K + k0 + off),
          (__attribute__((address_space(3))) void*)(lB + ch * 8), 16, 0, 0);
    }
    __syncthreads();
    const bf16x8* A8 = (const bf16x8*)lA;
    const bf16x8* B8 = (const bf16x8*)lB;
#pragma unroll
    for (int kk = 0; kk < 2; ++kk) {
      bf16x8 af[4], bfr[4];
#pragma unroll
      for (int i = 0; i < 4; ++i) af[i]  = A8[(wm + i * 16 + l16) * 8 + kk * 4 + quad];
#pragma unroll
      for (int j = 0; j < 4; ++j) bfr[j] = B8[(wn + j * 16 + l16) * 8 + kk * 4 + quad];
#pragma unroll
      for (int i = 0; i < 4; ++i)
#pragma unroll
        for (int j = 0; j < 4; ++j)
          acc[i][j] = __builtin_amdgcn_mfma_f32_16x16x32_bf16(af[i], bfr[j],
                                                              acc[i][j], 0, 0, 0);
    }
  }
#pragma unroll
  for (int i = 0; i < 4; ++i) {
#pragma unroll
    for (int rg = 0; rg < 4; ++rg) {
      int o = mt * 128 + wm + i * 16 + quad * 4 + rg;
      float bsv = outb[o] + cvec[b * 256 + o];
      size_t rowbase = (size_t)b * C_ * HW_ + (size_t)o * HW_;
#pragma unroll
      for (int j = 0; j < 4; ++j) {
        int n = nt * 128 + wn + j * 16 + l16;
        Cout[rowbase + n] = acc[i][j][rg] + bsv;
      }
    }
  }
}

// ---------------------------------------------------------------------------
extern "C" void kernel_launch(void* const* d_in, const int* in_sizes, int n_in,
                              void* d_out, int out_size, void* d_ws, size_t ws_size,
                              hipStream_t stream)
{
  const float* x    = (const float*)d_in[0];
  const float* gnw  = (const float*)d_in[1];
  const float* gnb  = (const float*)d_in[2];
  const float* qkvw = (const float*)d_in[3];
  const float* qkvb = (const float*)d_in[4];
  const float* outw = (const float*)d_in[5];
  const float* outb = (const float*)d_in[6];

  char* p = (char*)d_ws;
  float* scale  = (float*)p;            p += (size_t)B_ * C_ * 4;
  float* shiftv = (float*)p;            p += (size_t)B_ * C_ * 4;
  u16* cqkvw = (u16*)p;                 p += (size_t)384 * C_ * 2;
  float* Weff   = (float*)p;            p += (size_t)B_ * 256 * 256 * 4;   // 4 MB
  float* cvec   = (float*)p;            p += (size_t)B_ * 256 * 4;         // 16 KB
  u16* xn_t  = (u16*)p;                 p += (size_t)B_ * HW_ * C_ * 2;
  u16* kv    = (u16*)p;

  gn_stats_conv_kernel<<<1636, 256, 0, stream>>>(x, gnw, gnb, scale, shiftv,
                                                 qkvw, cqkvw, Weff);
  gn_transpose_kernel<<<dim3(32, 4, 16), 256, 0, stream>>>(x, xn_t, scale, shiftv);
  kv_gemm_kernel<<<dim3(32, 2, 16), 256, 0, stream>>>(cqkvw, xn_t, qkvb, kv);
  ctx_weff_kernel<<<64, 1024, 0, stream>>>(kv, outw, cqkvw, qkvb, Weff, cvec);
  wout_gemm_kernel<<<dim3(32, 2, 16), 256, 0, stream>>>(Weff, xn_t, outb, cvec,
                                                        (float*)d_out);
}